// Round 6
// baseline (494.865 us; speedup 1.0000x reference)
//
#include <hip/hip_runtime.h>
#include <hip/hip_bf16.h>
#include <math.h>

// B=4, T=2048, D=1024, E=8, F=1024, top_k=2
#define NTOK 8192   // B*T
#define D_DIM 1024
#define E_DIM 8
#define F_DIM 1024

// cnt is padded: counter for expert e lives at cnt[e*32] (128 B apart) so the
// 8 experts' global atomics land in different L2 lines (round 3: packed
// counters serialized 16384 atomics at ~12 ns each = 200 us).
#define CNT_STRIDE 32

typedef __attribute__((ext_vector_type(8))) short bf16x8;
typedef __attribute__((ext_vector_type(4))) float f32x4;

typedef const __attribute__((address_space(1))) unsigned int* as1_uint_ptr;
typedef __attribute__((address_space(3))) unsigned int* as3_uint_ptr;

__device__ __forceinline__ void async_load16(const void* g, void* l) {
    // per-lane global address; LDS dest = wave-uniform base + lane*16
    __builtin_amdgcn_global_load_lds((as1_uint_ptr)g, (as3_uint_ptr)l, 16, 0, 0);
}

__device__ __forceinline__ float bf2f(unsigned short b) {
    unsigned int u = ((unsigned int)b) << 16;
    return __builtin_bit_cast(float, u);
}
__device__ __forceinline__ unsigned short f2bf(float f) {
    __hip_bfloat16 h = __float2bfloat16(f);
    return __builtin_bit_cast(unsigned short, h);
}

// s_waitcnt immediates (gfx9 encoding): lgkm[11:8]=0xF (no wait), exp[6:4]=7
// (no wait), vmcnt[3:0]=N.  Round 6: double-buffered K-loop waits vmcnt(N) =
// "all but the N loads just issued for the next tile" instead of the
// __syncthreads vmcnt(0) full drain (round 5: MfmaUtil 26%, barrier-drain
// bound exactly like the m97 plateau).
#define WAIT_VM6() __builtin_amdgcn_s_waitcnt(0xF76)
#define WAIT_VM4() __builtin_amdgcn_s_waitcnt(0xF74)
#define WAIT_VM0() __builtin_amdgcn_s_waitcnt(0xF70)
#define CLOBBER()  asm volatile("" ::: "memory")

// LDS swizzle (round 5): stage lane s loads k-chunk (s&3)^((row>>1)&3);
// readers invert it -> 2-way bank access (free). Kept.

// ---------------- Kernel 1: router (wave-per-token) + fused x->bf16 cast ----
__global__ __launch_bounds__(512) void router_cast_kernel(
    const float* __restrict__ x,      // [NTOK][D]
    const float* __restrict__ Wr,     // [D][E]
    int* __restrict__ cnt,            // [E*CNT_STRIDE] padded counters
    int* __restrict__ tok_of,         // [E][NTOK] (tok2 = t*2+slot)
    float* __restrict__ wt2,          // [2*NTOK] weight by tok2
    unsigned short* __restrict__ xb)  // [NTOK][D] bf16
{
    __shared__ int lcnt[E_DIM];
    __shared__ int lbase[E_DIM];
    __shared__ int lbuf[E_DIM][64];   // 32 tokens * 2 slots max per expert

    const int tid = threadIdx.x;
    const int wv = tid >> 6;          // 0..7
    const int lane = tid & 63;
    if (tid < E_DIM) lcnt[tid] = 0;
    __syncthreads();

    #pragma unroll
    for (int it = 0; it < 4; ++it) {
        const int t = blockIdx.x * 32 + wv * 4 + it;
        const float* xrow = x + (size_t)t * D_DIM;
        unsigned short* xbrow = xb + (size_t)t * D_DIM;

        float p[E_DIM];
        #pragma unroll
        for (int e = 0; e < E_DIM; ++e) p[e] = 0.f;

        #pragma unroll
        for (int i = 0; i < 4; ++i) {
            const int d = i * 256 + lane * 4;
            float4 v = *(const float4*)(xrow + d);
            ushort4 o;
            o.x = f2bf(v.x); o.y = f2bf(v.y); o.z = f2bf(v.z); o.w = f2bf(v.w);
            *(ushort4*)(xbrow + d) = o;
            const float* wr = Wr + (size_t)d * E_DIM;
            float xv[4] = {v.x, v.y, v.z, v.w};
            #pragma unroll
            for (int q = 0; q < 4; ++q) {
                float4 w0 = *(const float4*)(wr + q * 8);
                float4 w1 = *(const float4*)(wr + q * 8 + 4);
                p[0] += xv[q] * w0.x; p[1] += xv[q] * w0.y;
                p[2] += xv[q] * w0.z; p[3] += xv[q] * w0.w;
                p[4] += xv[q] * w1.x; p[5] += xv[q] * w1.y;
                p[6] += xv[q] * w1.z; p[7] += xv[q] * w1.w;
            }
        }

        #pragma unroll
        for (int off = 32; off > 0; off >>= 1) {
            #pragma unroll
            for (int e = 0; e < E_DIM; ++e)
                p[e] += __shfl_xor(p[e], off, 64);
        }

        if (lane == 0) {
            float m = p[0];
            #pragma unroll
            for (int e = 1; e < E_DIM; ++e) m = fmaxf(m, p[e]);
            float pr[E_DIM], sum = 0.f;
            #pragma unroll
            for (int e = 0; e < E_DIM; ++e) { pr[e] = expf(p[e] - m); sum += pr[e]; }
            float inv = 1.f / sum;
            #pragma unroll
            for (int e = 0; e < E_DIM; ++e) pr[e] *= inv;
            // top-2 (strict > keeps lowest index on ties, matching lax.top_k)
            int e0 = 0;
            #pragma unroll
            for (int e = 1; e < E_DIM; ++e) if (pr[e] > pr[e0]) e0 = e;
            int e1 = (e0 == 0) ? 1 : 0;
            #pragma unroll
            for (int e = 0; e < E_DIM; ++e) { if (e != e0 && pr[e] > pr[e1]) e1 = e; }
            // second softmax over the two PROBABILITIES (faithful to reference)
            float b = expf(pr[e1] - pr[e0]);
            float w0 = 1.f / (1.f + b);
            float w1 = b / (1.f + b);
            int p0 = atomicAdd(&lcnt[e0], 1);
            lbuf[e0][p0] = t * 2 + 0;
            int p1 = atomicAdd(&lcnt[e1], 1);
            lbuf[e1][p1] = t * 2 + 1;
            wt2[t * 2 + 0] = w0;
            wt2[t * 2 + 1] = w1;
        }
    }
    __syncthreads();
    if (tid < E_DIM) lbase[tid] = atomicAdd(&cnt[tid * CNT_STRIDE], lcnt[tid]);
    __syncthreads();
    #pragma unroll
    for (int e = 0; e < E_DIM; ++e) {
        int n = lcnt[e];
        if (tid < n) tok_of[e * NTOK + lbase[e] + tid] = lbuf[e][tid];
    }
}

// ---------------- Kernel 3: cast+transpose weights -> [E][N][K] bf16 ------
__global__ __launch_bounds__(256) void transpose_cast_kernel(
    const float* __restrict__ Wg, const float* __restrict__ Wu,
    const float* __restrict__ Wd,
    unsigned short* __restrict__ WgT, unsigned short* __restrict__ WuT,
    unsigned short* __restrict__ WdT)
{
    const int m = blockIdx.z;
    const float* src;
    unsigned short* dst;
    if (m < 8)       { src = Wg + (size_t)m * 1048576;        dst = WgT + (size_t)m * 1048576; }
    else if (m < 16) { src = Wu + (size_t)(m - 8) * 1048576;  dst = WuT + (size_t)(m - 8) * 1048576; }
    else             { src = Wd + (size_t)(m - 16) * 1048576; dst = WdT + (size_t)(m - 16) * 1048576; }

    const int c0 = blockIdx.x * 64;   // src col tile (= dst row)
    const int r0 = blockIdx.y * 64;   // src row tile (= dst col)
    __shared__ float tile[64][65];
    const int tid = threadIdx.x;
    const int tr = tid >> 4;          // 0..15
    const int tc = (tid & 15) * 4;
    #pragma unroll
    for (int p = 0; p < 4; ++p) {
        float4 v = *(const float4*)(src + (size_t)(r0 + p * 16 + tr) * 1024 + c0 + tc);
        tile[p * 16 + tr][tc + 0] = v.x;
        tile[p * 16 + tr][tc + 1] = v.y;
        tile[p * 16 + tr][tc + 2] = v.z;
        tile[p * 16 + tr][tc + 3] = v.w;
    }
    __syncthreads();
    const int orow = tid >> 3;        // 0..31
    const int ocol = (tid & 7) * 8;
    #pragma unroll
    for (int p = 0; p < 2; ++p) {
        int fr = p * 32 + orow;       // dst row within tile (= src col)
        union { unsigned short s[8]; uint4 v; } pk;
        #pragma unroll
        for (int q = 0; q < 8; ++q) pk.s[q] = f2bf(tile[ocol + q][fr]);
        *(uint4*)&dst[(size_t)(c0 + fr) * 1024 + r0 + ocol] = pk.v;
    }
}

// ---------------- Kernel 4: fused gating+up MFMA GEMM + silu*mul ----------
// 128x128 tile, BK=32, 4 waves, double-buffered LDS + fine vmcnt.
__global__ __launch_bounds__(256, 3) void gateup_mfma(
    const unsigned short* __restrict__ xb,    // [NTOK][D] bf16
    const unsigned short* __restrict__ WgT,   // [E][F][D] bf16 (B^T)
    const unsigned short* __restrict__ WuT,   // [E][F][D] bf16
    const int* __restrict__ cnt,
    const int* __restrict__ tok_of,
    unsigned short* __restrict__ H)           // [2*NTOK][F] bf16
{
    const int e = blockIdx.y;
    const int rowTile = blockIdx.x >> 3;
    const int colTile = blockIdx.x & 7;
    const int rows = cnt[e * CNT_STRIDE];
    const int rowBase = rowTile * 128;
    if (rowBase >= rows) return;
    const int n0 = colTile * 128;

    __shared__ short As[2 * 4096];
    __shared__ short Bg[2 * 4096];
    __shared__ short Bu[2 * 4096];
    __shared__ int toks[128];

    const int tid = threadIdx.x;
    if (tid < 128) {
        int idx = rowBase + tid;
        toks[tid] = tok_of[e * NTOK + (idx < rows ? idx : rows - 1)];
    }
    __syncthreads();

    const int lane = tid & 63;
    const int w = tid >> 6;
    const int seg0 = w * 2, seg1 = w * 2 + 1;   // each wave stages 2 segs per buffer
    const int sr = lane >> 2;                   // 0..15 row within segment
    const int swz = (sr >> 1) & 3;
    const int sk = ((lane & 3) ^ swz) * 8;      // swizzled k-chunk (8 bf16 = 16B)

    const int ar0 = seg0 * 16 + sr;
    const int ar1 = seg1 * 16 + sr;
    const unsigned short* aG0 = xb + (size_t)(toks[ar0] >> 1) * D_DIM + sk;
    const unsigned short* aG1 = xb + (size_t)(toks[ar1] >> 1) * D_DIM + sk;
    const unsigned short* WgTe = WgT + (size_t)e * F_DIM * D_DIM;
    const unsigned short* WuTe = WuT + (size_t)e * F_DIM * D_DIM;
    const unsigned short* gG0 = WgTe + (size_t)(n0 + ar0) * D_DIM + sk;
    const unsigned short* gG1 = WgTe + (size_t)(n0 + ar1) * D_DIM + sk;
    const unsigned short* uG0 = WuTe + (size_t)(n0 + ar0) * D_DIM + sk;
    const unsigned short* uG1 = WuTe + (size_t)(n0 + ar1) * D_DIM + sk;

    const int mseg = (w >> 1) * 4;   // A segment base for this wave
    const int nseg = (w & 1) * 4;    // B segment base
    const int mbase = (w >> 1) * 64;
    const int nbase = (w & 1) * 64;
    const int fr = lane & 15;
    // reader offset within a segment (shorts): inverse of the staging swizzle
    const int rd = (4 * fr + ((lane >> 4) ^ ((fr >> 1) & 3))) * 8;

    f32x4 accg[4][4], accu[4][4];
    #pragma unroll
    for (int i = 0; i < 4; ++i)
        #pragma unroll
        for (int j = 0; j < 4; ++j) { accg[i][j] = (f32x4)(0.f); accu[i][j] = (f32x4)(0.f); }

#define STAGE_GU(k0, poff) do {                                  \
        async_load16(aG0 + (k0), &As[(poff) + seg0 * 512]);      \
        async_load16(aG1 + (k0), &As[(poff) + seg1 * 512]);      \
        async_load16(gG0 + (k0), &Bg[(poff) + seg0 * 512]);      \
        async_load16(gG1 + (k0), &Bg[(poff) + seg1 * 512]);      \
        async_load16(uG0 + (k0), &Bu[(poff) + seg0 * 512]);      \
        async_load16(uG1 + (k0), &Bu[(poff) + seg1 * 512]);      \
    } while (0)

    STAGE_GU(0, 0);
    int p = 0;
    for (int it = 0; it < D_DIM / 32; ++it) {
        const int poff = p << 12;
        if (it < D_DIM / 32 - 1) {
            STAGE_GU((it + 1) * 32, (p ^ 1) << 12);
            CLOBBER();
            WAIT_VM6();        // wait this tile's 6 loads; next tile's stay in flight
        } else {
            CLOBBER();
            WAIT_VM0();
        }
        __builtin_amdgcn_s_barrier();
        CLOBBER();

        bf16x8 a[4], g[4], u[4];
        #pragma unroll
        for (int i = 0; i < 4; ++i)
            a[i] = *(const bf16x8*)&As[poff + (mseg + i) * 512 + rd];
        #pragma unroll
        for (int j = 0; j < 4; ++j) {
            g[j] = *(const bf16x8*)&Bg[poff + (nseg + j) * 512 + rd];
            u[j] = *(const bf16x8*)&Bu[poff + (nseg + j) * 512 + rd];
        }
        #pragma unroll
        for (int i = 0; i < 4; ++i)
            #pragma unroll
            for (int j = 0; j < 4; ++j) {
                accg[i][j] = __builtin_amdgcn_mfma_f32_16x16x32_bf16(a[i], g[j], accg[i][j], 0, 0, 0);
                accu[i][j] = __builtin_amdgcn_mfma_f32_16x16x32_bf16(a[i], u[j], accu[i][j], 0, 0, 0);
            }

        CLOBBER();
        __builtin_amdgcn_s_barrier();   // all waves done reading buf p before overwrite
        p ^= 1;
    }
#undef STAGE_GU

    // epilogue: C/D layout col=lane&15, row=(lane>>4)*4+reg
    const int erow = (lane >> 4) * 4;
    #pragma unroll
    for (int i = 0; i < 4; ++i) {
        #pragma unroll
        for (int r = 0; r < 4; ++r) {
            int row = mbase + i * 16 + erow + r;
            int idx = rowBase + row;
            if (idx < rows) {
                int tok2 = toks[row];
                unsigned short* hrow = H + (size_t)tok2 * F_DIM + n0 + nbase;
                #pragma unroll
                for (int j = 0; j < 4; ++j) {
                    float gg = accg[i][j][r];
                    float uu = accu[i][j][r];
                    float h = gg / (1.f + __expf(-gg)) * uu;
                    hrow[j * 16 + fr] = f2bf(h);
                }
            }
        }
    }
}

// ---------------- Kernel 5: down MFMA GEMM + fused weighted scatter -------
// Double-buffered; epilogue does out += w * acc via native f32 atomics
// (exactly 2 contributions per element; replaces the combine kernel + Hd).
__global__ __launch_bounds__(256, 3) void down_mfma(
    const unsigned short* __restrict__ H,     // [2*NTOK][F] bf16
    const unsigned short* __restrict__ WdT,   // [E][D][F] bf16 (B^T)
    const int* __restrict__ cnt,
    const int* __restrict__ tok_of,
    const float* __restrict__ wt2,            // [2*NTOK]
    float* __restrict__ out)                  // [NTOK][D] f32 (pre-zeroed)
{
    const int e = blockIdx.y;
    const int rowTile = blockIdx.x >> 3;
    const int colTile = blockIdx.x & 7;
    const int rows = cnt[e * CNT_STRIDE];
    const int rowBase = rowTile * 128;
    if (rowBase >= rows) return;
    const int n0 = colTile * 128;

    __shared__ short As[2 * 4096];
    __shared__ short Bs[2 * 4096];
    __shared__ int toks[128];
    __shared__ float wts[128];

    const int tid = threadIdx.x;
    if (tid < 128) {
        int idx = rowBase + tid;
        int tok = tok_of[e * NTOK + (idx < rows ? idx : rows - 1)];
        toks[tid] = tok;
        wts[tid] = wt2[tok];
    }
    __syncthreads();

    const int lane = tid & 63;
    const int w = tid >> 6;
    const int seg0 = w * 2, seg1 = w * 2 + 1;
    const int sr = lane >> 2;
    const int swz = (sr >> 1) & 3;
    const int sk = ((lane & 3) ^ swz) * 8;

    const int ar0 = seg0 * 16 + sr;
    const int ar1 = seg1 * 16 + sr;
    const unsigned short* aG0 = H + (size_t)toks[ar0] * F_DIM + sk;
    const unsigned short* aG1 = H + (size_t)toks[ar1] * F_DIM + sk;
    const unsigned short* WdTe = WdT + (size_t)e * D_DIM * F_DIM;
    const unsigned short* bG0 = WdTe + (size_t)(n0 + ar0) * F_DIM + sk;
    const unsigned short* bG1 = WdTe + (size_t)(n0 + ar1) * F_DIM + sk;

    const int mseg = (w >> 1) * 4;
    const int nseg = (w & 1) * 4;
    const int mbase = (w >> 1) * 64;
    const int nbase = (w & 1) * 64;
    const int fr = lane & 15;
    const int rd = (4 * fr + ((lane >> 4) ^ ((fr >> 1) & 3))) * 8;

    f32x4 acc[4][4];
    #pragma unroll
    for (int i = 0; i < 4; ++i)
        #pragma unroll
        for (int j = 0; j < 4; ++j) acc[i][j] = (f32x4)(0.f);

#define STAGE_D(k0, poff) do {                                   \
        async_load16(aG0 + (k0), &As[(poff) + seg0 * 512]);      \
        async_load16(aG1 + (k0), &As[(poff) + seg1 * 512]);      \
        async_load16(bG0 + (k0), &Bs[(poff) + seg0 * 512]);      \
        async_load16(bG1 + (k0), &Bs[(poff) + seg1 * 512]);      \
    } while (0)

    STAGE_D(0, 0);
    int p = 0;
    for (int it = 0; it < F_DIM / 32; ++it) {
        const int poff = p << 12;
        if (it < F_DIM / 32 - 1) {
            STAGE_D((it + 1) * 32, (p ^ 1) << 12);
            CLOBBER();
            WAIT_VM4();
        } else {
            CLOBBER();
            WAIT_VM0();
        }
        __builtin_amdgcn_s_barrier();
        CLOBBER();

        bf16x8 a[4], b[4];
        #pragma unroll
        for (int i = 0; i < 4; ++i)
            a[i] = *(const bf16x8*)&As[poff + (mseg + i) * 512 + rd];
        #pragma unroll
        for (int j = 0; j < 4; ++j)
            b[j] = *(const bf16x8*)&Bs[poff + (nseg + j) * 512 + rd];
        #pragma unroll
        for (int i = 0; i < 4; ++i)
            #pragma unroll
            for (int j = 0; j < 4; ++j)
                acc[i][j] = __builtin_amdgcn_mfma_f32_16x16x32_bf16(a[i], b[j], acc[i][j], 0, 0, 0);

        CLOBBER();
        __builtin_amdgcn_s_barrier();
        p ^= 1;
    }
#undef STAGE_D

    const int erow = (lane >> 4) * 4;
    #pragma unroll
    for (int i = 0; i < 4; ++i) {
        #pragma unroll
        for (int r = 0; r < 4; ++r) {
            int row = mbase + i * 16 + erow + r;
            int idx = rowBase + row;
            if (idx < rows) {
                int tok2 = toks[row];
                float wgt = wts[row];
                float* orow = out + (size_t)(tok2 >> 1) * D_DIM + n0 + nbase;
                #pragma unroll
                for (int j = 0; j < 4; ++j)
                    unsafeAtomicAdd(&orow[j * 16 + fr], wgt * acc[i][j][r]);
            }
        }
    }
}

extern "C" void kernel_launch(void* const* d_in, const int* in_sizes, int n_in,
                              void* d_out, int out_size, void* d_ws, size_t ws_size,
                              hipStream_t stream) {
    const float* x  = (const float*)d_in[0];   // [B,T,D]
    const float* Wr = (const float*)d_in[1];   // [D,E]
    const float* Wg = (const float*)d_in[2];   // [E,D,F]
    const float* Wu = (const float*)d_in[3];   // [E,D,F]
    const float* Wd = (const float*)d_in[4];   // [E,F,D]
    float* out = (float*)d_out;

    char* ws = (char*)d_ws;
    int*   cnt    = (int*)ws;                                // 1 KB (padded counters)
    int*   tok_of = (int*)(ws + 1024);                       // 256 KB
    float* wt2    = (float*)(ws + 1024 + E_DIM * NTOK * 4);  // 64 KB
    char*  base   = ws + (1 << 20);
    unsigned short* xb  = (unsigned short*)(base);                    // 16 MB
    unsigned short* WgT = (unsigned short*)(base + (16ll << 20));     // 16 MB
    unsigned short* WuT = (unsigned short*)(base + (32ll << 20));     // 16 MB
    unsigned short* WdT = (unsigned short*)(base + (48ll << 20));     // 16 MB
    unsigned short* H   = (unsigned short*)(base + (64ll << 20));     // 32 MB
    // total ws use: 97 MB

    hipMemsetAsync(cnt, 0, E_DIM * CNT_STRIDE * sizeof(int), stream);
    hipMemsetAsync(d_out, 0, (size_t)out_size * sizeof(float), stream);

    router_cast_kernel<<<NTOK / 32, 512, 0, stream>>>(x, Wr, cnt, tok_of, wt2, xb);
    transpose_cast_kernel<<<dim3(16, 16, 24), 256, 0, stream>>>(Wg, Wu, Wd, WgT, WuT, WdT);

    gateup_mfma<<<dim3((NTOK / 128) * (F_DIM / 128), E_DIM), 256, 0, stream>>>(
        xb, WgT, WuT, cnt, tok_of, H);
    down_mfma<<<dim3((NTOK / 128) * (D_DIM / 128), E_DIM), 256, 0, stream>>>(
        H, WdT, cnt, tok_of, wt2, out);
}